// Round 2
// baseline (435.422 us; speedup 1.0000x reference)
//
#include <hip/hip_runtime.h>
#include <cstddef>
#include <cstdint>

#define S_LEN 2048
#define DMODEL 2048
#define NH 16
#define NKV 4
#define HD 128
#define BATCH 2
#define MROWS (BATCH * S_LEN) /* 4096 */
#define KVD (NKV * HD)        /* 512 */
#define QKVSTR 3072           /* fused qkv row stride (f16) */
#define NQT128 (S_LEN / 128)  /* 16 q-tiles of 128 rows */

typedef __attribute__((ext_vector_type(8))) short bf16x8;
typedef __attribute__((ext_vector_type(4))) float floatx4;
typedef __attribute__((ext_vector_type(8))) _Float16 half8;
typedef __attribute__((ext_vector_type(4))) _Float16 half4;
typedef __attribute__((ext_vector_type(2))) _Float16 half2v;

#define QSCALE 0.1275310255f /* log2(e)/sqrt(128): folds softmax scale + exp2 conversion */

__device__ inline short f2bf(float f) {
  union { float f; unsigned u; } v; v.f = f;
  unsigned r = v.u + 0x7FFFu + ((v.u >> 16) & 1u); // RNE
  return (short)(r >> 16);
}

__device__ inline half2v pack2h(float lo, float hi) {
  union { decltype(__builtin_amdgcn_cvt_pkrtz(0.f, 0.f)) raw; half2v h; } u;
  u.raw = __builtin_amdgcn_cvt_pkrtz(lo, hi);
  return u.h;
}

// CK-style address-space cast idiom for direct global->LDS DMA (16B/lane).
__device__ __forceinline__ void glds16(const void* g, void* l) {
  __builtin_amdgcn_global_load_lds(
      reinterpret_cast<const int __attribute__((address_space(1)))*>(
          reinterpret_cast<uintptr_t>(g)),
      reinterpret_cast<int __attribute__((address_space(3)))*>(
          reinterpret_cast<uintptr_t>(l)),
      16, 0, 0);
}

// ---------------------------------------------------------------------------
// cast_bf16: fp32 -> bf16 elementwise (8 elems/thread).
// ---------------------------------------------------------------------------
__global__ __launch_bounds__(256) void cast_bf16(
    const float* __restrict__ x, short* __restrict__ y)
{
  const size_t i = ((size_t)blockIdx.x * 256 + threadIdx.x) * 8;
  const float4 a = *(const float4*)(x + i);
  const float4 b = *(const float4*)(x + i + 4);
  bf16x8 o;
  o[0] = f2bf(a.x); o[1] = f2bf(a.y); o[2] = f2bf(a.z); o[3] = f2bf(a.w);
  o[4] = f2bf(b.x); o[5] = f2bf(b.y); o[6] = f2bf(b.z); o[7] = f2bf(b.w);
  *(bf16x8*)(y + i) = o;
}

// ---------------------------------------------------------------------------
// tcast: W fp32 [2048][N] -> Wt bf16 [N][2048] (transpose + cast), 64x64 tile.
// ---------------------------------------------------------------------------
__global__ __launch_bounds__(256) void tcast(
    const float* __restrict__ W, short* __restrict__ Wt, int N)
{
  __shared__ float Ts[64][65];
  const int n0 = blockIdx.x * 64, k0 = blockIdx.y * 64;
  const int tid = threadIdx.x;
#pragma unroll
  for (int it = 0; it < 4; ++it) {
    const int r = it * 16 + (tid >> 4);
    *(float4*)&Ts[r][(tid & 15) * 4] =
        *(const float4*)&W[(size_t)(k0 + r) * N + n0 + (tid & 15) * 4];
  }
  __syncthreads();
  const int n = tid >> 2, kg = (tid & 3) * 16;
  bf16x8 o0, o1;
#pragma unroll
  for (int e = 0; e < 8; ++e) o0[e] = f2bf(Ts[kg + e][n]);
#pragma unroll
  for (int e = 0; e < 8; ++e) o1[e] = f2bf(Ts[kg + 8 + e][n]);
  short* dst = Wt + (size_t)(n0 + n) * DMODEL + k0 + kg;
  *(bf16x8*)dst = o0;
  *(bf16x8*)(dst + 8) = o1;
}

// ---------------------------------------------------------------------------
// m97-style GEMM: C[M,N] = A[M,K] @ Bt[N,K]^T, bf16 operands staged via
// global_load_lds. 128x128 tile, BK=64, 4 waves of 4x4 mfma_f32_16x16x32_bf16.
// ---------------------------------------------------------------------------
template <bool OUTF16>
__global__ __launch_bounds__(256) void gemm_glds(
    const short* __restrict__ A, const short* __restrict__ Bt,
    void* __restrict__ Cv, int M, int N, int K)
{
  __shared__ short As[128 * 64];
  __shared__ short Bs[128 * 64];

  const int tid = threadIdx.x;
  const int wave = tid >> 6, lane = tid & 63;
  const int l16 = lane & 15, quad = lane >> 4;
  const int wm = (wave & 1) * 64, wn = (wave >> 1) * 64;
  const int m0 = blockIdx.y * 128, n0 = blockIdx.x * 128;

  const short* Ab = A + (size_t)(m0 + wave * 32 + (lane >> 3)) * K + ((lane & 7) << 3);
  const short* Bb = Bt + (size_t)(n0 + wave * 32 + (lane >> 3)) * K + ((lane & 7) << 3);
  short* Asw = As + wave * 32 * 64;
  short* Bsw = Bs + wave * 32 * 64;

  floatx4 acc[4][4];
#pragma unroll
  for (int i = 0; i < 4; ++i)
#pragma unroll
    for (int j = 0; j < 4; ++j)
#pragma unroll
      for (int r = 0; r < 4; ++r) acc[i][j][r] = 0.f;

  for (int k0 = 0; k0 < K; k0 += 64) {
    __syncthreads();
#pragma unroll
    for (int u = 0; u < 4; ++u) {
      glds16(Ab + (size_t)(u * 8) * K + k0, Asw + u * 8 * 64);
      glds16(Bb + (size_t)(u * 8) * K + k0, Bsw + u * 8 * 64);
    }
    __syncthreads();
#pragma unroll
    for (int c = 0; c < 2; ++c) {
      bf16x8 af[4], bf[4];
#pragma unroll
      for (int i = 0; i < 4; ++i)
        af[i] = *(const bf16x8*)&As[(wm + i * 16 + l16) * 64 + c * 32 + quad * 8];
#pragma unroll
      for (int j = 0; j < 4; ++j)
        bf[j] = *(const bf16x8*)&Bs[(wn + j * 16 + l16) * 64 + c * 32 + quad * 8];
#pragma unroll
      for (int i = 0; i < 4; ++i)
#pragma unroll
        for (int j = 0; j < 4; ++j)
          acc[i][j] = __builtin_amdgcn_mfma_f32_16x16x32_bf16(af[i], bf[j], acc[i][j], 0, 0, 0);
    }
  }

#pragma unroll
  for (int i = 0; i < 4; ++i)
#pragma unroll
    for (int r = 0; r < 4; ++r) {
      const int row = m0 + wm + i * 16 + (quad << 2) + r;
      if (OUTF16) {
        _Float16* cr = (_Float16*)Cv + (size_t)row * N + n0 + wn + l16;
#pragma unroll
        for (int j = 0; j < 4; ++j) cr[j * 16] = (_Float16)acc[i][j][r];
      } else {
        float* cr = (float*)Cv + (size_t)row * N + n0 + wn + l16;
#pragma unroll
        for (int j = 0; j < 4; ++j) cr[j * 16] = acc[i][j][r];
      }
    }
}

// ---------------------------------------------------------------------------
// rope_k: in-place RoPE on f16 k rows (stride QKVSTR, 4 heads). 4 rows/block.
// ---------------------------------------------------------------------------
__global__ __launch_bounds__(256) void rope_k(
    _Float16* __restrict__ kh, const float* __restrict__ cosp,
    const float* __restrict__ sinp)
{
  const int row = blockIdx.x * 4 + (threadIdx.x >> 6);
  const int sl = row & (S_LEN - 1);
  const int t = threadIdx.x & 63;
  const int h = t >> 4, g = t & 15;
  _Float16* base = kh + (size_t)row * QKVSTR + h * HD;
  const half8 x = *(const half8*)(base + 8 * g);
  const float4 c4 = *(const float4*)&cosp[sl * 64 + 4 * g];
  const float4 s4 = *(const float4*)&sinp[sl * 64 + 4 * g];
  const float p1[4] = {(float)x[0], (float)x[2], (float)x[4], (float)x[6]};
  const float p2[4] = {(float)x[1], (float)x[3], (float)x[5], (float)x[7]};
  const float cc[4] = {c4.x, c4.y, c4.z, c4.w};
  const float ss[4] = {s4.x, s4.y, s4.z, s4.w};
  __syncthreads();
  half4 o1, o2;
#pragma unroll
  for (int u = 0; u < 4; ++u) {
    o1[u] = (_Float16)(p1[u] * cc[u] - p2[u] * ss[u]);
    o2[u] = (_Float16)(p2[u] * cc[u] + p1[u] * ss[u]);
  }
  *(half4*)(base + 4 * g) = o1;
  *(half4*)(base + 64 + 4 * g) = o2;
}

// ---------------------------------------------------------------------------
// vtprep: f16 V rows (stride QKVSTR) -> f16 Vt [b][kvh][d][s], 64x64 tile.
// ---------------------------------------------------------------------------
__global__ __launch_bounds__(256) void vtprep(
    const _Float16* __restrict__ v, _Float16* __restrict__ Vt)
{
  __shared__ _Float16 Ts[64][72];
  const int s0 = blockIdx.x * 64, c0 = blockIdx.y * 64;
  const int tid = threadIdx.x;
#pragma unroll
  for (int it = 0; it < 4; ++it) {
    const int r = it * 16 + (tid >> 4);
    *(half4*)&Ts[r][(tid & 15) * 4] =
        *(const half4*)&v[(size_t)(s0 + r) * QKVSTR + c0 + (tid & 15) * 4];
  }
  __syncthreads();
  const int dr = tid >> 2, sg = tid & 3;
  const int d = c0 + dr;
  const int kvh = d >> 7, dd = d & 127;
  const int bb = s0 >> 11, sl = s0 & (S_LEN - 1);
  half8 t0, t1;
#pragma unroll
  for (int kk = 0; kk < 8; ++kk) t0[kk] = Ts[sg * 16 + kk][dr];
#pragma unroll
  for (int kk = 0; kk < 8; ++kk) t1[kk] = Ts[sg * 16 + 8 + kk][dr];
  _Float16* dst = Vt + ((size_t)(bb * NKV + kvh) * HD + dd) * S_LEN + sl + sg * 16;
  *(half8*)dst = t0;
  *(half8*)(dst + 8) = t1;
}

// ---------------------------------------------------------------------------
// MFMA flash attention v5: fat-wave retile. Round-1 post-mortem showed the
// kernel is LDS-traffic-bound (each wave re-reads the whole K/V tile; ~190KB
// LDS traffic per block-iter; MFMA only ~4% of issue). Fix: 32 q-rows/wave
// (was 16) -> every K/V fragment read from LDS feeds 2x the MFMAs, halving
// LDS read traffic AND barrier count per unit work; softmax row-ILP doubles.
//   - Block = 128 q-rows (4 waves x 32), kv-step 64.
//   - Balanced pairing kept: block = pair p -> passes qt=p, qt=15-p: exactly
//     (2p+2)+(32-2p) = 34 K-iterations per block. 256 uniform blocks, 1/CU.
//   - Double-buffered K/V, reg-prefetch, 1 barrier/iter, setprio, defer-rescale.
// LDS 90112 B (1 block/CU; round 1 proved 2-block TLP bought nothing).
// ---------------------------------------------------------------------------
__global__ __launch_bounds__(256, 1) void attn_mfma(
    const _Float16* __restrict__ Qh, const _Float16* __restrict__ Kr,
    const _Float16* __restrict__ Vt, const float* __restrict__ cosp,
    const float* __restrict__ sinp, short* __restrict__ aout)
{
  __shared__ _Float16 Ks[2][64][136];   // [buf][kv][d], 272B rows
  __shared__ _Float16 Vs[2][128][72];   // [buf][d][kv], 144B rows
  __shared__ _Float16 Ps[4][32][72];    // per-wave P buffer [q][kv]

  const int tid = threadIdx.x;
  const int wave = tid >> 6, lane = tid & 63;
  const int l16 = lane & 15, quad = lane >> 4;
  const int pair = blockIdx.x;          // 0..7
  const int h = blockIdx.y, b = blockIdx.z;
  const int kvh = h >> 2;

  // staging assignments (pass-independent)
  const int skr = tid >> 2;
  const int skc = (tid & 3) * 32;
  const _Float16* kgp = Kr + (size_t)(b * S_LEN + skr) * QKVSTR + kvh * HD + skc;
  const int svr = tid >> 1;
  const int svc = (tid & 1) * 32;
  const _Float16* vgp = Vt + ((size_t)(b * NKV + kvh) * HD + svr) * S_LEN + svc;

  for (int pass = 0; pass < 2; ++pass) {
    const int qt = pass ? (NQT128 - 1 - pair) : pair; // 128-row tile index
    const int qbase = qt * 128 + wave * 32;

    // ---- Q A-frags with in-register RoPE + scale, 2 row-subtiles ----
    half8 qf[2][4];
#pragma unroll
    for (int r16 = 0; r16 < 2; ++r16) {
      const int srow = qbase + r16 * 16 + l16;
      const _Float16* qraw = Qh + (size_t)(b * S_LEN + srow) * QKVSTR + h * HD;
      const int co = (srow & (S_LEN - 1)) * 64;
#pragma unroll
      for (int cc = 0; cc < 2; ++cc) {
        const half8 r0 = *(const half8*)(qraw + cc * 64 + quad * 16);
        const half8 r1 = *(const half8*)(qraw + cc * 64 + quad * 16 + 8);
        const float4 c0 = *(const float4*)&cosp[co + cc * 32 + quad * 8];
        const float4 c1 = *(const float4*)&cosp[co + cc * 32 + quad * 8 + 4];
        const float4 s0 = *(const float4*)&sinp[co + cc * 32 + quad * 8];
        const float4 s1 = *(const float4*)&sinp[co + cc * 32 + quad * 8 + 4];
        const float cA[8] = {c0.x, c0.y, c0.z, c0.w, c1.x, c1.y, c1.z, c1.w};
        const float sA[8] = {s0.x, s0.y, s0.z, s0.w, s1.x, s1.y, s1.z, s1.w};
#pragma unroll
        for (int j = 0; j < 8; ++j) {
          const float p1 = (float)((j < 4) ? r0[2 * j] : r1[2 * (j - 4)]);
          const float p2 = (float)((j < 4) ? r0[2 * j + 1] : r1[2 * (j - 4) + 1]);
          qf[r16][cc][j]     = (_Float16)((p1 * cA[j] - p2 * sA[j]) * QSCALE);
          qf[r16][cc + 2][j] = (_Float16)((p2 * cA[j] + p1 * sA[j]) * QSCALE);
        }
      }
    }

    floatx4 o[2][8];
#pragma unroll
    for (int r16 = 0; r16 < 2; ++r16)
#pragma unroll
      for (int d = 0; d < 8; ++d) o[r16][d] = (floatx4){0.f, 0.f, 0.f, 0.f};
    float m_run[2][4], l_run[2][4];
#pragma unroll
    for (int r16 = 0; r16 < 2; ++r16)
#pragma unroll
      for (int r = 0; r < 4; ++r) { m_run[r16][r] = -3e38f; l_run[r16][r] = 0.f; }

    // ---- prologue: stage tile 0 into buffer 0 ----
    __syncthreads(); // prior pass's LDS reads complete
    {
      _Float16* dst = &Ks[0][skr][skc];
#pragma unroll
      for (int u = 0; u < 4; ++u)
        *(half8*)(dst + u * 8) = *(const half8*)(kgp + u * 8);
      _Float16* dv = &Vs[0][svr][svc];
#pragma unroll
      for (int u = 0; u < 4; ++u)
        *(half8*)(dv + u * 8) = *(const half8*)(vgp + u * 8);
    }
    __syncthreads();

    const int ktmax = 2 * qt + 1;
    int cur = 0;
    for (int kt = 0; kt <= ktmax; ++kt) {
      const int k0 = kt * 64;
      const bool pre = (kt < ktmax);

      // ---- issue next tile's global loads NOW; consumed after compute ----
      half8 kreg[4], vreg[4];
      if (pre) {
        const _Float16* g = kgp + (size_t)(kt + 1) * 64 * QKVSTR;
#pragma unroll
        for (int u = 0; u < 4; ++u) kreg[u] = *(const half8*)(g + u * 8);
        const _Float16* gv = vgp + (kt + 1) * 64;
#pragma unroll
        for (int u = 0; u < 4; ++u) vreg[u] = *(const half8*)(gv + u * 8);
      }

      // ---- QK^T: K-frags read once, reused by both row-subtiles ----
      floatx4 s[2][4];
#pragma unroll
      for (int r16 = 0; r16 < 2; ++r16)
#pragma unroll
        for (int i = 0; i < 4; ++i) s[r16][i] = (floatx4){0.f, 0.f, 0.f, 0.f};
      __builtin_amdgcn_s_setprio(1);
#pragma unroll
      for (int i = 0; i < 4; ++i)
#pragma unroll
        for (int c = 0; c < 4; ++c) {
          const half8 kf = *(const half8*)&Ks[cur][i * 16 + l16][quad * 8 + c * 32];
          s[0][i] = __builtin_amdgcn_mfma_f32_16x16x32_f16(qf[0][c], kf, s[0][i], 0, 0, 0);
          s[1][i] = __builtin_amdgcn_mfma_f32_16x16x32_f16(qf[1][c], kf, s[1][i], 0, 0, 0);
        }
      __builtin_amdgcn_s_setprio(0);

      if (kt >= 2 * qt) { // diagonal 128x128 block spans two kv-iters
#pragma unroll
        for (int r16 = 0; r16 < 2; ++r16)
#pragma unroll
          for (int i = 0; i < 4; ++i) {
            const int kpos = k0 + i * 16 + l16;
#pragma unroll
            for (int r = 0; r < 4; ++r)
              if (kpos > qbase + r16 * 16 + quad * 4 + r) s[r16][i][r] = -3.0e38f;
          }
      }

      // ---- online softmax, 8 independent rows per lane ----
      float p[2][4][4];
#pragma unroll
      for (int r16 = 0; r16 < 2; ++r16)
#pragma unroll
        for (int r = 0; r < 4; ++r) {
          float rm = fmaxf(fmaxf(s[r16][0][r], s[r16][1][r]),
                           fmaxf(s[r16][2][r], s[r16][3][r]));
          rm = fmaxf(rm, __shfl_xor(rm, 1));
          rm = fmaxf(rm, __shfl_xor(rm, 2));
          rm = fmaxf(rm, __shfl_xor(rm, 4));
          rm = fmaxf(rm, __shfl_xor(rm, 8));
          if (rm > m_run[r16][r]) { // defer-rescale
            const float alpha = exp2f(m_run[r16][r] - rm);
            m_run[r16][r] = rm;
            l_run[r16][r] *= alpha;
#pragma unroll
            for (int d = 0; d < 8; ++d) o[r16][d][r] *= alpha;
          }
          float rs = 0.f;
#pragma unroll
          for (int i = 0; i < 4; ++i) {
            p[r16][i][r] = exp2f(s[r16][i][r] - m_run[r16][r]);
            rs += p[r16][i][r];
          }
          rs += __shfl_xor(rs, 1);
          rs += __shfl_xor(rs, 2);
          rs += __shfl_xor(rs, 4);
          rs += __shfl_xor(rs, 8);
          l_run[r16][r] += rs;
        }

      // ---- P repack to LDS (f16), per row-subtile ----
      const int odd = l16 & 1;
      const int cbase = l16 & 14;
#pragma unroll
      for (int r16 = 0; r16 < 2; ++r16)
#pragma unroll
        for (int i = 0; i < 4; ++i) {
#pragma unroll
          for (int rr = 0; rr < 2; ++rr) {
            const float send = odd ? p[r16][i][rr] : p[r16][i][2 + rr];
            const float recv = __shfl_xor(send, 1);
            const float lo = odd ? recv : p[r16][i][rr];
            const float hi = odd ? p[r16][i][2 + rr] : recv;
            *(half2v*)&Ps[wave][r16 * 16 + quad * 4 + 2 * odd + rr][i * 16 + cbase] =
                pack2h(lo, hi);
          }
        }
      half8 pf[2][2];
#pragma unroll
      for (int r16 = 0; r16 < 2; ++r16) {
        pf[r16][0] = *(const half8*)&Ps[wave][r16 * 16 + l16][quad * 8];
        pf[r16][1] = *(const half8*)&Ps[wave][r16 * 16 + l16][32 + quad * 8];
      }

      // ---- PV: V-frags read once, reused by both row-subtiles ----
      __builtin_amdgcn_s_setprio(1);
#pragma unroll
      for (int d = 0; d < 8; ++d) {
        const half8 vf0 = *(const half8*)&Vs[cur][d * 16 + l16][quad * 8];
        const half8 vf1 = *(const half8*)&Vs[cur][d * 16 + l16][32 + quad * 8];
        o[0][d] = __builtin_amdgcn_mfma_f32_16x16x32_f16(pf[0][0], vf0, o[0][d], 0, 0, 0);
        o[0][d] = __builtin_amdgcn_mfma_f32_16x16x32_f16(pf[0][1], vf1, o[0][d], 0, 0, 0);
        o[1][d] = __builtin_amdgcn_mfma_f32_16x16x32_f16(pf[1][0], vf0, o[1][d], 0, 0, 0);
        o[1][d] = __builtin_amdgcn_mfma_f32_16x16x32_f16(pf[1][1], vf1, o[1][d], 0, 0, 0);
      }
      __builtin_amdgcn_s_setprio(0);

      // ---- land the prefetched tile into the other buffer ----
      if (pre) {
        _Float16* dst = &Ks[cur ^ 1][skr][skc];
#pragma unroll
        for (int u = 0; u < 4; ++u) *(half8*)(dst + u * 8) = kreg[u];
        _Float16* dv = &Vs[cur ^ 1][svr][svc];
#pragma unroll
        for (int u = 0; u < 4; ++u) *(half8*)(dv + u * 8) = vreg[u];
      }
      __syncthreads(); // single barrier/iter
      cur ^= 1;
    }

    // ---- epilogue for this pass ----
#pragma unroll
    for (int r16 = 0; r16 < 2; ++r16) {
      float inv[4];
#pragma unroll
      for (int r = 0; r < 4; ++r) inv[r] = 1.0f / l_run[r16][r];
#pragma unroll
      for (int d = 0; d < 8; ++d)
#pragma unroll
        for (int r = 0; r < 4; ++r)
          aout[(size_t)(b * S_LEN + qbase + r16 * 16 + quad * 4 + r) * DMODEL +
               h * HD + d * 16 + l16] = f2bf(o[r16][d][r] * inv[r]);
    }
  }
}

// ---------------------------------------------------------------------------
extern "C" void kernel_launch(void* const* d_in, const int* in_sizes, int n_in,
                              void* d_out, int out_size, void* d_ws, size_t ws_size,
                              hipStream_t stream) {
  const float* hs   = (const float*)d_in[0];
  const float* cosp = (const float*)d_in[2];
  const float* sinp = (const float*)d_in[3];
  const float* Wq   = (const float*)d_in[4];
  const float* Wk   = (const float*)d_in[5];
  const float* Wv   = (const float*)d_in[6];
  const float* Wo   = (const float*)d_in[7];
  float* out = (float*)d_out;

  // ws layout (58.7 MB):
  //   hsb bf16 [4096][2048] 16.8M (dead after qkv GEMM -> aliased by ao)
  //   Wt  bf16 [3072][2048] 12.6M (fused Wq|Wk|Wv transposed; later Wo)
  //   qkv f16  [4096][3072] 25.2M (q raw | k roped in-place | v)
  //   Vt  f16  [2][4][128][2048] 4.2M
  char* w = (char*)d_ws;
  short*    hsb = (short*)w;
  short*    Wt  = (short*)(w + 16777216);
  _Float16* qkv = (_Float16*)(w + 29360128);
  _Float16* Vt  = (_Float16*)(w + 54525952);
  short*    ao  = hsb; // safe alias: hsb dead after the fused qkv GEMM

  _Float16* qh = qkv;
  _Float16* kh = qkv + 2048;
  _Float16* vh = qkv + 2560;

  dim3 blk(256);
  cast_bf16<<<MROWS * DMODEL / (8 * 256), blk, 0, stream>>>(hs, hsb);
  tcast<<<dim3(DMODEL / 64, DMODEL / 64), blk, 0, stream>>>(Wq, Wt, DMODEL);
  tcast<<<dim3(KVD / 64, DMODEL / 64), blk, 0, stream>>>(Wk, Wt + (size_t)2048 * DMODEL, KVD);
  tcast<<<dim3(KVD / 64, DMODEL / 64), blk, 0, stream>>>(Wv, Wt + (size_t)2560 * DMODEL, KVD);
  gemm_glds<true><<<dim3(QKVSTR / 128, MROWS / 128), blk, 0, stream>>>(hsb, Wt, qkv, MROWS, QKVSTR, DMODEL);
  rope_k<<<MROWS / 4, blk, 0, stream>>>(kh, cosp, sinp);
  vtprep<<<dim3(MROWS / 64, KVD / 64), blk, 0, stream>>>(vh, Vt);
  attn_mfma<<<dim3(NQT128 / 2, NH, BATCH), blk, 0, stream>>>(qh, kh, Vt, cosp, sinp, ao);
  tcast<<<dim3(DMODEL / 64, DMODEL / 64), blk, 0, stream>>>(Wo, Wt, DMODEL);
  gemm_glds<false><<<dim3(DMODEL / 128, MROWS / 128), blk, 0, stream>>>(ao, Wt, out, MROWS, DMODEL, DMODEL);
}

// Round 3
// 399.013 us; speedup vs baseline: 1.0912x; 1.0912x over previous
//
#include <hip/hip_runtime.h>
#include <cstddef>
#include <cstdint>

#define S_LEN 2048
#define DMODEL 2048
#define NH 16
#define NKV 4
#define HD 128
#define BATCH 2
#define MROWS (BATCH * S_LEN) /* 4096 */
#define KVD (NKV * HD)        /* 512 */
#define QKVSTR 3072           /* fused qkv row stride (f16) */
#define NQT (S_LEN / 64)      /* 32 q-tiles of 64 rows */

typedef __attribute__((ext_vector_type(8))) short bf16x8;
typedef __attribute__((ext_vector_type(4))) float floatx4;
typedef __attribute__((ext_vector_type(8))) _Float16 half8;
typedef __attribute__((ext_vector_type(4))) _Float16 half4;
typedef __attribute__((ext_vector_type(2))) _Float16 half2v;

#define QSCALE 0.1275310255f /* log2(e)/sqrt(128): folds softmax scale + exp2 conversion */

__device__ inline short f2bf(float f) {
  union { float f; unsigned u; } v; v.f = f;
  unsigned r = v.u + 0x7FFFu + ((v.u >> 16) & 1u); // RNE
  return (short)(r >> 16);
}

__device__ inline half2v pack2h(float lo, float hi) {
  union { decltype(__builtin_amdgcn_cvt_pkrtz(0.f, 0.f)) raw; half2v h; } u;
  u.raw = __builtin_amdgcn_cvt_pkrtz(lo, hi);
  return u.h;
}

// CK-style address-space cast idiom for direct global->LDS DMA (16B/lane).
__device__ __forceinline__ void glds16(const void* g, void* l) {
  __builtin_amdgcn_global_load_lds(
      reinterpret_cast<const int __attribute__((address_space(1)))*>(
          reinterpret_cast<uintptr_t>(g)),
      reinterpret_cast<int __attribute__((address_space(3)))*>(
          reinterpret_cast<uintptr_t>(l)),
      16, 0, 0);
}

// ---------------------------------------------------------------------------
// cast_bf16: fp32 -> bf16 elementwise (8 elems/thread).
// ---------------------------------------------------------------------------
__global__ __launch_bounds__(256) void cast_bf16(
    const float* __restrict__ x, short* __restrict__ y)
{
  const size_t i = ((size_t)blockIdx.x * 256 + threadIdx.x) * 8;
  const float4 a = *(const float4*)(x + i);
  const float4 b = *(const float4*)(x + i + 4);
  bf16x8 o;
  o[0] = f2bf(a.x); o[1] = f2bf(a.y); o[2] = f2bf(a.z); o[3] = f2bf(a.w);
  o[4] = f2bf(b.x); o[5] = f2bf(b.y); o[6] = f2bf(b.z); o[7] = f2bf(b.w);
  *(bf16x8*)(y + i) = o;
}

// ---------------------------------------------------------------------------
// tcast: W fp32 [2048][N] -> Wt bf16 [N][2048] (transpose + cast), 64x64 tile.
// ---------------------------------------------------------------------------
__global__ __launch_bounds__(256) void tcast(
    const float* __restrict__ W, short* __restrict__ Wt, int N)
{
  __shared__ float Ts[64][65];
  const int n0 = blockIdx.x * 64, k0 = blockIdx.y * 64;
  const int tid = threadIdx.x;
#pragma unroll
  for (int it = 0; it < 4; ++it) {
    const int r = it * 16 + (tid >> 4);
    *(float4*)&Ts[r][(tid & 15) * 4] =
        *(const float4*)&W[(size_t)(k0 + r) * N + n0 + (tid & 15) * 4];
  }
  __syncthreads();
  const int n = tid >> 2, kg = (tid & 3) * 16;
  bf16x8 o0, o1;
#pragma unroll
  for (int e = 0; e < 8; ++e) o0[e] = f2bf(Ts[kg + e][n]);
#pragma unroll
  for (int e = 0; e < 8; ++e) o1[e] = f2bf(Ts[kg + 8 + e][n]);
  short* dst = Wt + (size_t)(n0 + n) * DMODEL + k0 + kg;
  *(bf16x8*)dst = o0;
  *(bf16x8*)(dst + 8) = o1;
}

// ---------------------------------------------------------------------------
// m97-style GEMM: C[M,N] = A[M,K] @ Bt[N,K]^T, bf16 operands staged via
// global_load_lds. 128x128 tile, BK=64, 4 waves of 4x4 mfma_f32_16x16x32_bf16.
// ---------------------------------------------------------------------------
template <bool OUTF16>
__global__ __launch_bounds__(256) void gemm_glds(
    const short* __restrict__ A, const short* __restrict__ Bt,
    void* __restrict__ Cv, int M, int N, int K)
{
  __shared__ short As[128 * 64];
  __shared__ short Bs[128 * 64];

  const int tid = threadIdx.x;
  const int wave = tid >> 6, lane = tid & 63;
  const int l16 = lane & 15, quad = lane >> 4;
  const int wm = (wave & 1) * 64, wn = (wave >> 1) * 64;
  const int m0 = blockIdx.y * 128, n0 = blockIdx.x * 128;

  const short* Ab = A + (size_t)(m0 + wave * 32 + (lane >> 3)) * K + ((lane & 7) << 3);
  const short* Bb = Bt + (size_t)(n0 + wave * 32 + (lane >> 3)) * K + ((lane & 7) << 3);
  short* Asw = As + wave * 32 * 64;
  short* Bsw = Bs + wave * 32 * 64;

  floatx4 acc[4][4];
#pragma unroll
  for (int i = 0; i < 4; ++i)
#pragma unroll
    for (int j = 0; j < 4; ++j)
#pragma unroll
      for (int r = 0; r < 4; ++r) acc[i][j][r] = 0.f;

  for (int k0 = 0; k0 < K; k0 += 64) {
    __syncthreads();
#pragma unroll
    for (int u = 0; u < 4; ++u) {
      glds16(Ab + (size_t)(u * 8) * K + k0, Asw + u * 8 * 64);
      glds16(Bb + (size_t)(u * 8) * K + k0, Bsw + u * 8 * 64);
    }
    __syncthreads();
#pragma unroll
    for (int c = 0; c < 2; ++c) {
      bf16x8 af[4], bf[4];
#pragma unroll
      for (int i = 0; i < 4; ++i)
        af[i] = *(const bf16x8*)&As[(wm + i * 16 + l16) * 64 + c * 32 + quad * 8];
#pragma unroll
      for (int j = 0; j < 4; ++j)
        bf[j] = *(const bf16x8*)&Bs[(wn + j * 16 + l16) * 64 + c * 32 + quad * 8];
#pragma unroll
      for (int i = 0; i < 4; ++i)
#pragma unroll
        for (int j = 0; j < 4; ++j)
          acc[i][j] = __builtin_amdgcn_mfma_f32_16x16x32_bf16(af[i], bf[j], acc[i][j], 0, 0, 0);
    }
  }

#pragma unroll
  for (int i = 0; i < 4; ++i)
#pragma unroll
    for (int r = 0; r < 4; ++r) {
      const int row = m0 + wm + i * 16 + (quad << 2) + r;
      if (OUTF16) {
        _Float16* cr = (_Float16*)Cv + (size_t)row * N + n0 + wn + l16;
#pragma unroll
        for (int j = 0; j < 4; ++j) cr[j * 16] = (_Float16)acc[i][j][r];
      } else {
        float* cr = (float*)Cv + (size_t)row * N + n0 + wn + l16;
#pragma unroll
        for (int j = 0; j < 4; ++j) cr[j * 16] = acc[i][j][r];
      }
    }
}

// ---------------------------------------------------------------------------
// rope_k: in-place RoPE on f16 k rows (stride QKVSTR, 4 heads). 4 rows/block.
// ---------------------------------------------------------------------------
__global__ __launch_bounds__(256) void rope_k(
    _Float16* __restrict__ kh, const float* __restrict__ cosp,
    const float* __restrict__ sinp)
{
  const int row = blockIdx.x * 4 + (threadIdx.x >> 6);
  const int sl = row & (S_LEN - 1);
  const int t = threadIdx.x & 63;
  const int h = t >> 4, g = t & 15;
  _Float16* base = kh + (size_t)row * QKVSTR + h * HD;
  const half8 x = *(const half8*)(base + 8 * g);
  const float4 c4 = *(const float4*)&cosp[sl * 64 + 4 * g];
  const float4 s4 = *(const float4*)&sinp[sl * 64 + 4 * g];
  const float p1[4] = {(float)x[0], (float)x[2], (float)x[4], (float)x[6]};
  const float p2[4] = {(float)x[1], (float)x[3], (float)x[5], (float)x[7]};
  const float cc[4] = {c4.x, c4.y, c4.z, c4.w};
  const float ss[4] = {s4.x, s4.y, s4.z, s4.w};
  __syncthreads();
  half4 o1, o2;
#pragma unroll
  for (int u = 0; u < 4; ++u) {
    o1[u] = (_Float16)(p1[u] * cc[u] - p2[u] * ss[u]);
    o2[u] = (_Float16)(p2[u] * cc[u] + p1[u] * ss[u]);
  }
  *(half4*)(base + 4 * g) = o1;
  *(half4*)(base + 64 + 4 * g) = o2;
}

// ---------------------------------------------------------------------------
// vtprep: f16 V rows (stride QKVSTR) -> f16 Vt [b][kvh][d][s], 64x64 tile.
// ---------------------------------------------------------------------------
__global__ __launch_bounds__(256) void vtprep(
    const _Float16* __restrict__ v, _Float16* __restrict__ Vt)
{
  __shared__ _Float16 Ts[64][72];
  const int s0 = blockIdx.x * 64, c0 = blockIdx.y * 64;
  const int tid = threadIdx.x;
#pragma unroll
  for (int it = 0; it < 4; ++it) {
    const int r = it * 16 + (tid >> 4);
    *(half4*)&Ts[r][(tid & 15) * 4] =
        *(const half4*)&v[(size_t)(s0 + r) * QKVSTR + c0 + (tid & 15) * 4];
  }
  __syncthreads();
  const int dr = tid >> 2, sg = tid & 3;
  const int d = c0 + dr;
  const int kvh = d >> 7, dd = d & 127;
  const int bb = s0 >> 11, sl = s0 & (S_LEN - 1);
  half8 t0, t1;
#pragma unroll
  for (int kk = 0; kk < 8; ++kk) t0[kk] = Ts[sg * 16 + kk][dr];
#pragma unroll
  for (int kk = 0; kk < 8; ++kk) t1[kk] = Ts[sg * 16 + 8 + kk][dr];
  _Float16* dst = Vt + ((size_t)(bb * NKV + kvh) * HD + dd) * S_LEN + sl + sg * 16;
  *(half8*)dst = t0;
  *(half8*)(dst + 8) = t1;
}

// ---------------------------------------------------------------------------
// MFMA flash attention v6: round-0 proven tile structure (16 q-rows/wave,
// single-buffered K/V, 2 barriers/iter, VGPR~72, LDS 45056 -> 3 blocks/CU),
// but UNPAIRED grid. Round 0/1/2 post-mortems: the kernel is chain-latency
// bound; only resident-wave TLP hides it; paired 512-block grid capped
// residency at exactly 2 blocks/CU even though LDS/VGPR allow 3.
//   - Grid 1024 blocks (h, qt, b); each block owns one 64-row q-tile with
//     causal trip count qt+1. qt = 31-blockIdx.y so the longest blocks
//     dispatch first and short blocks backfill the tail.
//   - Occupancy target: 3 blocks/CU (12 waves) steady state.
// ---------------------------------------------------------------------------
__global__ __launch_bounds__(256, 3) void attn_mfma(
    const _Float16* __restrict__ Qh, const _Float16* __restrict__ Kr,
    const _Float16* __restrict__ Vt, const float* __restrict__ cosp,
    const float* __restrict__ sinp, short* __restrict__ aout)
{
  __shared__ _Float16 Ks[64][136];   // [kv][d], 272B rows
  __shared__ _Float16 Vs[128][72];   // [d][kv], 144B rows
  __shared__ _Float16 Ps[4][16][72]; // per-wave P buffer [q][kv]

  const int tid = threadIdx.x;
  const int wave = tid >> 6, lane = tid & 63;
  const int l16 = lane & 15, quad = lane >> 4;
  const int h = blockIdx.x, b = blockIdx.z;
  const int qt = (NQT - 1) - blockIdx.y; // longest-first dispatch
  const int kvh = h >> 2;

  // staging assignments
  const int skr = tid >> 2;
  const int skc = (tid & 3) * 32;
  const _Float16* kgp = Kr + (size_t)(b * S_LEN + skr) * QKVSTR + kvh * HD + skc;
  const int svr = tid >> 1;
  const int svc = (tid & 1) * 32;
  const _Float16* vgp = Vt + ((size_t)(b * NKV + kvh) * HD + svr) * S_LEN + svc;

  const int q0 = qt * 64 + wave * 16;
  const int srow = q0 + l16;

  // ---- Q A-frags with in-register RoPE + scale ----
  half8 qf[4];
  {
    const _Float16* qraw = Qh + (size_t)(b * S_LEN + srow) * QKVSTR + h * HD;
    const int co = (srow & (S_LEN - 1)) * 64;
#pragma unroll
    for (int cc = 0; cc < 2; ++cc) {
      const half8 r0 = *(const half8*)(qraw + cc * 64 + quad * 16);
      const half8 r1 = *(const half8*)(qraw + cc * 64 + quad * 16 + 8);
      const float4 c0 = *(const float4*)&cosp[co + cc * 32 + quad * 8];
      const float4 c1 = *(const float4*)&cosp[co + cc * 32 + quad * 8 + 4];
      const float4 s0 = *(const float4*)&sinp[co + cc * 32 + quad * 8];
      const float4 s1 = *(const float4*)&sinp[co + cc * 32 + quad * 8 + 4];
      const float cA[8] = {c0.x, c0.y, c0.z, c0.w, c1.x, c1.y, c1.z, c1.w};
      const float sA[8] = {s0.x, s0.y, s0.z, s0.w, s1.x, s1.y, s1.z, s1.w};
#pragma unroll
      for (int j = 0; j < 8; ++j) {
        const float p1 = (float)((j < 4) ? r0[2 * j] : r1[2 * (j - 4)]);
        const float p2 = (float)((j < 4) ? r0[2 * j + 1] : r1[2 * (j - 4) + 1]);
        qf[cc][j]     = (_Float16)((p1 * cA[j] - p2 * sA[j]) * QSCALE);
        qf[cc + 2][j] = (_Float16)((p2 * cA[j] + p1 * sA[j]) * QSCALE);
      }
    }
  }

  floatx4 o[8];
#pragma unroll
  for (int d = 0; d < 8; ++d) o[d] = (floatx4){0.f, 0.f, 0.f, 0.f};
  float m_run[4] = {-3e38f, -3e38f, -3e38f, -3e38f};
  float l_run[4] = {0.f, 0.f, 0.f, 0.f};

  for (int kt = 0; kt <= qt; ++kt) {
    const int k0 = kt * 64;
    __syncthreads(); // prior iteration's frag reads complete
    {
      const _Float16* g = kgp + (size_t)k0 * QKVSTR;
      _Float16* dst = &Ks[skr][skc];
#pragma unroll
      for (int u = 0; u < 4; ++u)
        *(half8*)(dst + u * 8) = *(const half8*)(g + u * 8);
    }
    {
      const _Float16* g = vgp + k0;
      _Float16* dst = &Vs[svr][svc];
#pragma unroll
      for (int u = 0; u < 4; ++u)
        *(half8*)(dst + u * 8) = *(const half8*)(g + u * 8);
    }
    __syncthreads();

    floatx4 s[4];
    __builtin_amdgcn_s_setprio(1);
#pragma unroll
    for (int i = 0; i < 4; ++i) {
      s[i] = (floatx4){0.f, 0.f, 0.f, 0.f};
#pragma unroll
      for (int c = 0; c < 4; ++c) {
        const half8 kf = *(const half8*)&Ks[i * 16 + l16][quad * 8 + c * 32];
        s[i] = __builtin_amdgcn_mfma_f32_16x16x32_f16(qf[c], kf, s[i], 0, 0, 0);
      }
    }
    __builtin_amdgcn_s_setprio(0);

    if (kt == qt) {
#pragma unroll
      for (int i = 0; i < 4; ++i) {
        const int kpos = k0 + i * 16 + l16;
#pragma unroll
        for (int r = 0; r < 4; ++r)
          if (kpos > q0 + quad * 4 + r) s[i][r] = -3.0e38f;
      }
    }

    float p[4][4];
#pragma unroll
    for (int r = 0; r < 4; ++r) {
      float rm = fmaxf(fmaxf(s[0][r], s[1][r]), fmaxf(s[2][r], s[3][r]));
      rm = fmaxf(rm, __shfl_xor(rm, 1));
      rm = fmaxf(rm, __shfl_xor(rm, 2));
      rm = fmaxf(rm, __shfl_xor(rm, 4));
      rm = fmaxf(rm, __shfl_xor(rm, 8));
      if (rm > m_run[r]) { // defer-rescale
        const float alpha = exp2f(m_run[r] - rm);
        m_run[r] = rm;
        l_run[r] *= alpha;
#pragma unroll
        for (int d = 0; d < 8; ++d) o[d][r] *= alpha;
      }
      float rs = 0.f;
#pragma unroll
      for (int i = 0; i < 4; ++i) { p[i][r] = exp2f(s[i][r] - m_run[r]); rs += p[i][r]; }
      rs += __shfl_xor(rs, 1);
      rs += __shfl_xor(rs, 2);
      rs += __shfl_xor(rs, 4);
      rs += __shfl_xor(rs, 8);
      l_run[r] += rs;
    }

    const int odd = l16 & 1;
    const int cbase = l16 & 14;
#pragma unroll
    for (int i = 0; i < 4; ++i) {
#pragma unroll
      for (int rr = 0; rr < 2; ++rr) {
        const float send = odd ? p[i][rr] : p[i][2 + rr];
        const float recv = __shfl_xor(send, 1);
        const float lo = odd ? recv : p[i][rr];
        const float hi = odd ? p[i][2 + rr] : recv;
        *(half2v*)&Ps[wave][quad * 4 + 2 * odd + rr][i * 16 + cbase] = pack2h(lo, hi);
      }
    }
    const half8 pf0 = *(const half8*)&Ps[wave][l16][quad * 8];
    const half8 pf1 = *(const half8*)&Ps[wave][l16][32 + quad * 8];

    __builtin_amdgcn_s_setprio(1);
#pragma unroll
    for (int d = 0; d < 8; ++d) {
      const half8 vf0 = *(const half8*)&Vs[d * 16 + l16][quad * 8];
      const half8 vf1 = *(const half8*)&Vs[d * 16 + l16][32 + quad * 8];
      o[d] = __builtin_amdgcn_mfma_f32_16x16x32_f16(pf0, vf0, o[d], 0, 0, 0);
      o[d] = __builtin_amdgcn_mfma_f32_16x16x32_f16(pf1, vf1, o[d], 0, 0, 0);
    }
    __builtin_amdgcn_s_setprio(0);
  }

  // ---- epilogue ----
  float inv[4];
#pragma unroll
  for (int r = 0; r < 4; ++r) inv[r] = 1.0f / l_run[r];
#pragma unroll
  for (int d = 0; d < 8; ++d)
#pragma unroll
    for (int r = 0; r < 4; ++r)
      aout[(size_t)(b * S_LEN + q0 + quad * 4 + r) * DMODEL + h * HD + d * 16 + l16] =
          f2bf(o[d][r] * inv[r]);
}

// ---------------------------------------------------------------------------
extern "C" void kernel_launch(void* const* d_in, const int* in_sizes, int n_in,
                              void* d_out, int out_size, void* d_ws, size_t ws_size,
                              hipStream_t stream) {
  const float* hs   = (const float*)d_in[0];
  const float* cosp = (const float*)d_in[2];
  const float* sinp = (const float*)d_in[3];
  const float* Wq   = (const float*)d_in[4];
  const float* Wk   = (const float*)d_in[5];
  const float* Wv   = (const float*)d_in[6];
  const float* Wo   = (const float*)d_in[7];
  float* out = (float*)d_out;

  // ws layout (58.7 MB):
  //   hsb bf16 [4096][2048] 16.8M (dead after qkv GEMM -> aliased by ao)
  //   Wt  bf16 [3072][2048] 12.6M (fused Wq|Wk|Wv transposed; later Wo)
  //   qkv f16  [4096][3072] 25.2M (q raw | k roped in-place | v)
  //   Vt  f16  [2][4][128][2048] 4.2M
  char* w = (char*)d_ws;
  short*    hsb = (short*)w;
  short*    Wt  = (short*)(w + 16777216);
  _Float16* qkv = (_Float16*)(w + 29360128);
  _Float16* Vt  = (_Float16*)(w + 54525952);
  short*    ao  = hsb; // safe alias: hsb dead after the fused qkv GEMM

  _Float16* qh = qkv;
  _Float16* kh = qkv + 2048;
  _Float16* vh = qkv + 2560;

  dim3 blk(256);
  cast_bf16<<<MROWS * DMODEL / (8 * 256), blk, 0, stream>>>(hs, hsb);
  tcast<<<dim3(DMODEL / 64, DMODEL / 64), blk, 0, stream>>>(Wq, Wt, DMODEL);
  tcast<<<dim3(KVD / 64, DMODEL / 64), blk, 0, stream>>>(Wk, Wt + (size_t)2048 * DMODEL, KVD);
  tcast<<<dim3(KVD / 64, DMODEL / 64), blk, 0, stream>>>(Wv, Wt + (size_t)2560 * DMODEL, KVD);
  gemm_glds<true><<<dim3(QKVSTR / 128, MROWS / 128), blk, 0, stream>>>(hsb, Wt, qkv, MROWS, QKVSTR, DMODEL);
  rope_k<<<MROWS / 4, blk, 0, stream>>>(kh, cosp, sinp);
  vtprep<<<dim3(MROWS / 64, KVD / 64), blk, 0, stream>>>(vh, Vt);
  attn_mfma<<<dim3(NH, NQT, BATCH), blk, 0, stream>>>(qh, kh, Vt, cosp, sinp, ao);
  tcast<<<dim3(DMODEL / 64, DMODEL / 64), blk, 0, stream>>>(Wo, Wt, DMODEL);
  gemm_glds<false><<<dim3(DMODEL / 128, MROWS / 128), blk, 0, stream>>>(ao, Wt, out, MROWS, DMODEL, DMODEL);
}

// Round 5
// 369.420 us; speedup vs baseline: 1.1787x; 1.0801x over previous
//
#include <hip/hip_runtime.h>
#include <cstddef>
#include <cstdint>

#define S_LEN 2048
#define DMODEL 2048
#define NH 16
#define NKV 4
#define HD 128
#define BATCH 2
#define MROWS (BATCH * S_LEN) /* 4096 */
#define KVD (NKV * HD)        /* 512 */
#define QKVSTR 3072           /* fused qkv row stride (f16) */
#define NQT (S_LEN / 64)      /* 32 q-tiles of 64 rows */

typedef __attribute__((ext_vector_type(8))) short bf16x8;
typedef __attribute__((ext_vector_type(4))) short shortx4;
typedef __attribute__((ext_vector_type(4))) float floatx4;
typedef __attribute__((ext_vector_type(8))) _Float16 half8;
typedef __attribute__((ext_vector_type(4))) _Float16 half4;
typedef __attribute__((ext_vector_type(2))) _Float16 half2v;

#define QSCALE 0.1275310255f /* log2(e)/sqrt(128): folds softmax scale + exp2 conversion */

__device__ inline short f2bf(float f) {
  union { float f; unsigned u; } v; v.f = f;
  unsigned r = v.u + 0x7FFFu + ((v.u >> 16) & 1u); // RNE
  return (short)(r >> 16);
}

__device__ inline half2v pack2h(float lo, float hi) {
  union { decltype(__builtin_amdgcn_cvt_pkrtz(0.f, 0.f)) raw; half2v h; } u;
  u.raw = __builtin_amdgcn_cvt_pkrtz(lo, hi);
  return u.h;
}

// CK-style address-space cast idiom for direct global->LDS DMA (16B/lane).
__device__ __forceinline__ void glds16(const void* g, void* l) {
  __builtin_amdgcn_global_load_lds(
      reinterpret_cast<const int __attribute__((address_space(1)))*>(
          reinterpret_cast<uintptr_t>(g)),
      reinterpret_cast<int __attribute__((address_space(3)))*>(
          reinterpret_cast<uintptr_t>(l)),
      16, 0, 0);
}

// ---------------------------------------------------------------------------
// cast_bf16: fp32 -> bf16 elementwise (8 elems/thread).
// ---------------------------------------------------------------------------
__global__ __launch_bounds__(256) void cast_bf16(
    const float* __restrict__ x, short* __restrict__ y)
{
  const size_t i = ((size_t)blockIdx.x * 256 + threadIdx.x) * 8;
  const float4 a = *(const float4*)(x + i);
  const float4 b = *(const float4*)(x + i + 4);
  bf16x8 o;
  o[0] = f2bf(a.x); o[1] = f2bf(a.y); o[2] = f2bf(a.z); o[3] = f2bf(a.w);
  o[4] = f2bf(b.x); o[5] = f2bf(b.y); o[6] = f2bf(b.z); o[7] = f2bf(b.w);
  *(bf16x8*)(y + i) = o;
}

// ---------------------------------------------------------------------------
// tcast: W fp32 [2048][N] -> Wt bf16 [N][2048] (transpose + cast), 64x64 tile.
// ---------------------------------------------------------------------------
__global__ __launch_bounds__(256) void tcast(
    const float* __restrict__ W, short* __restrict__ Wt, int N)
{
  __shared__ float Ts[64][65];
  const int n0 = blockIdx.x * 64, k0 = blockIdx.y * 64;
  const int tid = threadIdx.x;
#pragma unroll
  for (int it = 0; it < 4; ++it) {
    const int r = it * 16 + (tid >> 4);
    *(float4*)&Ts[r][(tid & 15) * 4] =
        *(const float4*)&W[(size_t)(k0 + r) * N + n0 + (tid & 15) * 4];
  }
  __syncthreads();
  const int n = tid >> 2, kg = (tid & 3) * 16;
  bf16x8 o0, o1;
#pragma unroll
  for (int e = 0; e < 8; ++e) o0[e] = f2bf(Ts[kg + e][n]);
#pragma unroll
  for (int e = 0; e < 8; ++e) o1[e] = f2bf(Ts[kg + 8 + e][n]);
  short* dst = Wt + (size_t)(n0 + n) * DMODEL + k0 + kg;
  *(bf16x8*)dst = o0;
  *(bf16x8*)(dst + 8) = o1;
}

// ---------------------------------------------------------------------------
// m97-style GEMM: C[M,N] = A[M,K] @ Bt[N,K]^T, bf16 operands staged via
// global_load_lds. 128x128 tile, BK=64, 4 waves of 4x4 mfma_f32_16x16x32_bf16.
// ---------------------------------------------------------------------------
template <bool OUTF16>
__global__ __launch_bounds__(256) void gemm_glds(
    const short* __restrict__ A, const short* __restrict__ Bt,
    void* __restrict__ Cv, int M, int N, int K)
{
  __shared__ short As[128 * 64];
  __shared__ short Bs[128 * 64];

  const int tid = threadIdx.x;
  const int wave = tid >> 6, lane = tid & 63;
  const int l16 = lane & 15, quad = lane >> 4;
  const int wm = (wave & 1) * 64, wn = (wave >> 1) * 64;
  const int m0 = blockIdx.y * 128, n0 = blockIdx.x * 128;

  const short* Ab = A + (size_t)(m0 + wave * 32 + (lane >> 3)) * K + ((lane & 7) << 3);
  const short* Bb = Bt + (size_t)(n0 + wave * 32 + (lane >> 3)) * K + ((lane & 7) << 3);
  short* Asw = As + wave * 32 * 64;
  short* Bsw = Bs + wave * 32 * 64;

  floatx4 acc[4][4];
#pragma unroll
  for (int i = 0; i < 4; ++i)
#pragma unroll
    for (int j = 0; j < 4; ++j)
#pragma unroll
      for (int r = 0; r < 4; ++r) acc[i][j][r] = 0.f;

  for (int k0 = 0; k0 < K; k0 += 64) {
    __syncthreads();
#pragma unroll
    for (int u = 0; u < 4; ++u) {
      glds16(Ab + (size_t)(u * 8) * K + k0, Asw + u * 8 * 64);
      glds16(Bb + (size_t)(u * 8) * K + k0, Bsw + u * 8 * 64);
    }
    __syncthreads();
#pragma unroll
    for (int c = 0; c < 2; ++c) {
      bf16x8 af[4], bf[4];
#pragma unroll
      for (int i = 0; i < 4; ++i)
        af[i] = *(const bf16x8*)&As[(wm + i * 16 + l16) * 64 + c * 32 + quad * 8];
#pragma unroll
      for (int j = 0; j < 4; ++j)
        bf[j] = *(const bf16x8*)&Bs[(wn + j * 16 + l16) * 64 + c * 32 + quad * 8];
#pragma unroll
      for (int i = 0; i < 4; ++i)
#pragma unroll
        for (int j = 0; j < 4; ++j)
          acc[i][j] = __builtin_amdgcn_mfma_f32_16x16x32_bf16(af[i], bf[j], acc[i][j], 0, 0, 0);
    }
  }

#pragma unroll
  for (int i = 0; i < 4; ++i)
#pragma unroll
    for (int r = 0; r < 4; ++r) {
      const int row = m0 + wm + i * 16 + (quad << 2) + r;
      if (OUTF16) {
        _Float16* cr = (_Float16*)Cv + (size_t)row * N + n0 + wn + l16;
#pragma unroll
        for (int j = 0; j < 4; ++j) cr[j * 16] = (_Float16)acc[i][j][r];
      } else {
        float* cr = (float*)Cv + (size_t)row * N + n0 + wn + l16;
#pragma unroll
        for (int j = 0; j < 4; ++j) cr[j * 16] = acc[i][j][r];
      }
    }
}

// ---------------------------------------------------------------------------
// rope_k: in-place RoPE on f16 k rows (stride QKVSTR, 4 heads). 4 rows/block.
// ---------------------------------------------------------------------------
__global__ __launch_bounds__(256) void rope_k(
    _Float16* __restrict__ kh, const float* __restrict__ cosp,
    const float* __restrict__ sinp)
{
  const int row = blockIdx.x * 4 + (threadIdx.x >> 6);
  const int sl = row & (S_LEN - 1);
  const int t = threadIdx.x & 63;
  const int h = t >> 4, g = t & 15;
  _Float16* base = kh + (size_t)row * QKVSTR + h * HD;
  const half8 x = *(const half8*)(base + 8 * g);
  const float4 c4 = *(const float4*)&cosp[sl * 64 + 4 * g];
  const float4 s4 = *(const float4*)&sinp[sl * 64 + 4 * g];
  const float p1[4] = {(float)x[0], (float)x[2], (float)x[4], (float)x[6]};
  const float p2[4] = {(float)x[1], (float)x[3], (float)x[5], (float)x[7]};
  const float cc[4] = {c4.x, c4.y, c4.z, c4.w};
  const float ss[4] = {s4.x, s4.y, s4.z, s4.w};
  __syncthreads();
  half4 o1, o2;
#pragma unroll
  for (int u = 0; u < 4; ++u) {
    o1[u] = (_Float16)(p1[u] * cc[u] - p2[u] * ss[u]);
    o2[u] = (_Float16)(p2[u] * cc[u] + p1[u] * ss[u]);
  }
  *(half4*)(base + 4 * g) = o1;
  *(half4*)(base + 64 + 4 * g) = o2;
}

// ---------------------------------------------------------------------------
// vtprep: f16 V rows (stride QKVSTR) -> f16 Vt [b][kvh][d][s], 64x64 tile.
// ---------------------------------------------------------------------------
__global__ __launch_bounds__(256) void vtprep(
    const _Float16* __restrict__ v, _Float16* __restrict__ Vt)
{
  __shared__ _Float16 Ts[64][72];
  const int s0 = blockIdx.x * 64, c0 = blockIdx.y * 64;
  const int tid = threadIdx.x;
#pragma unroll
  for (int it = 0; it < 4; ++it) {
    const int r = it * 16 + (tid >> 4);
    *(half4*)&Ts[r][(tid & 15) * 4] =
        *(const half4*)&v[(size_t)(s0 + r) * QKVSTR + c0 + (tid & 15) * 4];
  }
  __syncthreads();
  const int dr = tid >> 2, sg = tid & 3;
  const int d = c0 + dr;
  const int kvh = d >> 7, dd = d & 127;
  const int bb = s0 >> 11, sl = s0 & (S_LEN - 1);
  half8 t0, t1;
#pragma unroll
  for (int kk = 0; kk < 8; ++kk) t0[kk] = Ts[sg * 16 + kk][dr];
#pragma unroll
  for (int kk = 0; kk < 8; ++kk) t1[kk] = Ts[sg * 16 + 8 + kk][dr];
  _Float16* dst = Vt + ((size_t)(bb * NKV + kvh) * HD + dd) * S_LEN + sl + sg * 16;
  *(half8*)dst = t0;
  *(half8*)(dst + 8) = t1;
}

// ---------------------------------------------------------------------------
// MFMA flash attention v7: round-0 structure (paired 512-block grid, 2/CU,
// single-buffered K/V, 2 barriers/iter) + SWAPPED-OPERAND core (T12).
// s = mfma(K, Q): D col = q = l16 -> each lane owns ONE q-row; its 64 kv
// scores live in 16 regs spread across the 4 quads. This removes per iter
// per wave: 36 of 40 shuffles, 16 selects, half the P-LDS writes, and
// shortens the softmax dependency chain (2 shfls instead of two 4-deep
// chains per row x 4 rows). PV also swapped: o = mfma(V^T, P^T) -> O^T in
// regs, packed 8B epilogue stores. K/V/P LDS read patterns are bit-identical
// to the proven round-0 ones. LDS 45056.
// ---------------------------------------------------------------------------
__global__ __launch_bounds__(256, 3) void attn_mfma(
    const _Float16* __restrict__ Qh, const _Float16* __restrict__ Kr,
    const _Float16* __restrict__ Vt, const float* __restrict__ cosp,
    const float* __restrict__ sinp, short* __restrict__ aout)
{
  __shared__ _Float16 Ks[64][136];   // [kv][d], 272B rows
  __shared__ _Float16 Vs[128][72];   // [d][kv], 144B rows
  __shared__ _Float16 Ps[4][16][72]; // per-wave P^T buffer [q][kv]

  const int tid = threadIdx.x;
  const int wave = tid >> 6, lane = tid & 63;
  const int l16 = lane & 15, quad = lane >> 4;
  const int pair = blockIdx.x;
  const int h = blockIdx.y, b = blockIdx.z;
  const int kvh = h >> 2;

  // staging assignments (pass-independent)
  const int skr = tid >> 2;
  const int skc = (tid & 3) * 32;
  const _Float16* kgp = Kr + (size_t)(b * S_LEN + skr) * QKVSTR + kvh * HD + skc;
  const int svr = tid >> 1;
  const int svc = (tid & 1) * 32;
  const _Float16* vgp = Vt + ((size_t)(b * NKV + kvh) * HD + svr) * S_LEN + svc;

  for (int pass = 0; pass < 2; ++pass) {
    const int qt = pass ? (NQT - 1 - pair) : pair;
    const int q0 = qt * 64 + wave * 16;
    const int srow = q0 + l16; // this lane's q-row

    // ---- Q B-frags with in-register RoPE + scale ----
    // qf[c][j] = roped Q[srow][d = c*32 + quad*8 + j] * QSCALE
    half8 qf[4];
    {
      const _Float16* qraw = Qh + (size_t)(b * S_LEN + srow) * QKVSTR + h * HD;
      const int co = (srow & (S_LEN - 1)) * 64;
#pragma unroll
      for (int cc = 0; cc < 2; ++cc) {
        const half8 r0 = *(const half8*)(qraw + cc * 64 + quad * 16);
        const half8 r1 = *(const half8*)(qraw + cc * 64 + quad * 16 + 8);
        const float4 c0 = *(const float4*)&cosp[co + cc * 32 + quad * 8];
        const float4 c1 = *(const float4*)&cosp[co + cc * 32 + quad * 8 + 4];
        const float4 s0 = *(const float4*)&sinp[co + cc * 32 + quad * 8];
        const float4 s1 = *(const float4*)&sinp[co + cc * 32 + quad * 8 + 4];
        const float cA[8] = {c0.x, c0.y, c0.z, c0.w, c1.x, c1.y, c1.z, c1.w};
        const float sA[8] = {s0.x, s0.y, s0.z, s0.w, s1.x, s1.y, s1.z, s1.w};
#pragma unroll
        for (int j = 0; j < 8; ++j) {
          const float p1 = (float)((j < 4) ? r0[2 * j] : r1[2 * (j - 4)]);
          const float p2 = (float)((j < 4) ? r0[2 * j + 1] : r1[2 * (j - 4) + 1]);
          qf[cc][j]     = (_Float16)((p1 * cA[j] - p2 * sA[j]) * QSCALE);
          qf[cc + 2][j] = (_Float16)((p2 * cA[j] + p1 * sA[j]) * QSCALE);
        }
      }
    }

    floatx4 o[8]; // o[dblk][r]: O^T[d = dblk*16 + quad*4 + r][q = l16]
#pragma unroll
    for (int d = 0; d < 8; ++d) o[d] = (floatx4){0.f, 0.f, 0.f, 0.f};
    float m_run = -3e38f, l_run = 0.f;

    for (int kt = 0; kt <= qt; ++kt) {
      const int k0 = kt * 64;
      __syncthreads(); // prior frag reads (incl. previous pass) complete
      {
        const _Float16* g = kgp + (size_t)k0 * QKVSTR;
        _Float16* dst = &Ks[skr][skc];
#pragma unroll
        for (int u = 0; u < 4; ++u)
          *(half8*)(dst + u * 8) = *(const half8*)(g + u * 8);
      }
      {
        const _Float16* g = vgp + k0;
        _Float16* dst = &Vs[svr][svc];
#pragma unroll
        for (int u = 0; u < 4; ++u)
          *(half8*)(dst + u * 8) = *(const half8*)(g + u * 8);
      }
      __syncthreads();

      // ---- QK^T swapped: s[i][r] = S[kv = k0 + i*16 + quad*4 + r][q = srow]
      floatx4 s[4];
      __builtin_amdgcn_s_setprio(1);
#pragma unroll
      for (int i = 0; i < 4; ++i) {
        s[i] = (floatx4){0.f, 0.f, 0.f, 0.f};
#pragma unroll
        for (int c = 0; c < 4; ++c) {
          const half8 kf = *(const half8*)&Ks[i * 16 + l16][quad * 8 + c * 32];
          s[i] = __builtin_amdgcn_mfma_f32_16x16x32_f16(kf, qf[c], s[i], 0, 0, 0);
        }
      }
      __builtin_amdgcn_s_setprio(0);

      if (kt == qt) { // causal mask: kv > q
#pragma unroll
        for (int i = 0; i < 4; ++i) {
          const int kvbase = k0 + i * 16 + quad * 4;
#pragma unroll
          for (int r = 0; r < 4; ++r)
            if (kvbase + r > srow) s[i][r] = -3.0e38f;
        }
      }

      // ---- online softmax: lane owns one q-row; 16 in-lane + 2 shfls ----
      float m0 = fmaxf(fmaxf(s[0][0], s[0][1]), fmaxf(s[0][2], s[0][3]));
      float m1 = fmaxf(fmaxf(s[1][0], s[1][1]), fmaxf(s[1][2], s[1][3]));
      float m2 = fmaxf(fmaxf(s[2][0], s[2][1]), fmaxf(s[2][2], s[2][3]));
      float m3 = fmaxf(fmaxf(s[3][0], s[3][1]), fmaxf(s[3][2], s[3][3]));
      float rm = fmaxf(fmaxf(m0, m1), fmaxf(m2, m3));
      rm = fmaxf(rm, __shfl_xor(rm, 16));
      rm = fmaxf(rm, __shfl_xor(rm, 32));
      if (rm > m_run) { // defer-rescale
        const float alpha = exp2f(m_run - rm);
        m_run = rm;
        l_run *= alpha;
#pragma unroll
        for (int d = 0; d < 8; ++d)
#pragma unroll
          for (int r = 0; r < 4; ++r) o[d][r] *= alpha;
      }
      float p[4][4];
      float rs = 0.f;
#pragma unroll
      for (int i = 0; i < 4; ++i)
#pragma unroll
        for (int r = 0; r < 4; ++r) {
          p[i][r] = exp2f(s[i][r] - m_run);
          rs += p[i][r];
        }
      rs += __shfl_xor(rs, 16);
      rs += __shfl_xor(rs, 32);
      l_run += rs;

      // ---- P^T to LDS: lane writes its own row's kv slots (8 x 4B) ----
#pragma unroll
      for (int i = 0; i < 4; ++i) {
        *(half2v*)&Ps[wave][l16][i * 16 + quad * 4]     = pack2h(p[i][0], p[i][1]);
        *(half2v*)&Ps[wave][l16][i * 16 + quad * 4 + 2] = pack2h(p[i][2], p[i][3]);
      }
      const half8 pf0 = *(const half8*)&Ps[wave][l16][quad * 8];
      const half8 pf1 = *(const half8*)&Ps[wave][l16][32 + quad * 8];

      // ---- PV swapped: o[dblk] = V^T . P^T ----
      __builtin_amdgcn_s_setprio(1);
#pragma unroll
      for (int d = 0; d < 8; ++d) {
        const half8 vf0 = *(const half8*)&Vs[d * 16 + l16][quad * 8];
        const half8 vf1 = *(const half8*)&Vs[d * 16 + l16][32 + quad * 8];
        o[d] = __builtin_amdgcn_mfma_f32_16x16x32_f16(vf0, pf0, o[d], 0, 0, 0);
        o[d] = __builtin_amdgcn_mfma_f32_16x16x32_f16(vf1, pf1, o[d], 0, 0, 0);
      }
      __builtin_amdgcn_s_setprio(0);
    }

    // ---- epilogue: lane writes row srow, 8 packed 8B stores ----
    const float inv = 1.0f / l_run;
    short* orow = aout + (size_t)(b * S_LEN + srow) * DMODEL + h * HD;
#pragma unroll
    for (int d = 0; d < 8; ++d) {
      shortx4 pk;
      pk[0] = f2bf(o[d][0] * inv);
      pk[1] = f2bf(o[d][1] * inv);
      pk[2] = f2bf(o[d][2] * inv);
      pk[3] = f2bf(o[d][3] * inv);
      *(shortx4*)(orow + d * 16 + quad * 4) = pk;
    }
  }
}

// ---------------------------------------------------------------------------
extern "C" void kernel_launch(void* const* d_in, const int* in_sizes, int n_in,
                              void* d_out, int out_size, void* d_ws, size_t ws_size,
                              hipStream_t stream) {
  const float* hs   = (const float*)d_in[0];
  const float* cosp = (const float*)d_in[2];
  const float* sinp = (const float*)d_in[3];
  const float* Wq   = (const float*)d_in[4];
  const float* Wk   = (const float*)d_in[5];
  const float* Wv   = (const float*)d_in[6];
  const float* Wo   = (const float*)d_in[7];
  float* out = (float*)d_out;

  // ws layout (58.7 MB):
  //   hsb bf16 [4096][2048] 16.8M (dead after qkv GEMM -> aliased by ao)
  //   Wt  bf16 [3072][2048] 12.6M (fused Wq|Wk|Wv transposed; later Wo)
  //   qkv f16  [4096][3072] 25.2M (q raw | k roped in-place | v)
  //   Vt  f16  [2][4][128][2048] 4.2M
  char* w = (char*)d_ws;
  short*    hsb = (short*)w;
  short*    Wt  = (short*)(w + 16777216);
  _Float16* qkv = (_Float16*)(w + 29360128);
  _Float16* Vt  = (_Float16*)(w + 54525952);
  short*    ao  = hsb; // safe alias: hsb dead after the fused qkv GEMM

  _Float16* qh = qkv;
  _Float16* kh = qkv + 2048;
  _Float16* vh = qkv + 2560;

  dim3 blk(256);
  cast_bf16<<<MROWS * DMODEL / (8 * 256), blk, 0, stream>>>(hs, hsb);
  tcast<<<dim3(DMODEL / 64, DMODEL / 64), blk, 0, stream>>>(Wq, Wt, DMODEL);
  tcast<<<dim3(KVD / 64, DMODEL / 64), blk, 0, stream>>>(Wk, Wt + (size_t)2048 * DMODEL, KVD);
  tcast<<<dim3(KVD / 64, DMODEL / 64), blk, 0, stream>>>(Wv, Wt + (size_t)2560 * DMODEL, KVD);
  gemm_glds<true><<<dim3(QKVSTR / 128, MROWS / 128), blk, 0, stream>>>(hsb, Wt, qkv, MROWS, QKVSTR, DMODEL);
  rope_k<<<MROWS / 4, blk, 0, stream>>>(kh, cosp, sinp);
  vtprep<<<dim3(MROWS / 64, KVD / 64), blk, 0, stream>>>(vh, Vt);
  attn_mfma<<<dim3(NQT / 2, NH, BATCH), blk, 0, stream>>>(qh, kh, Vt, cosp, sinp, ao);
  tcast<<<dim3(DMODEL / 64, DMODEL / 64), blk, 0, stream>>>(Wo, Wt, DMODEL);
  gemm_glds<false><<<dim3(DMODEL / 128, MROWS / 128), blk, 0, stream>>>(ao, Wt, out, MROWS, DMODEL, DMODEL);
}